// Round 1
// baseline (227.474 us; speedup 1.0000x reference)
//
#include <hip/hip_runtime.h>
#include <math.h>

#define BS 256

// Workspace layout:
//   [0, 64)              : 4 doubles (sum_lp, sum_la, sum_lw, sum_ls) + pad
//   [64, 64+4*nb)        : blockSums (int)
//   [64+4*nb, 64+8*nb)   : blockOffsets (int)

__global__ void block_sum_kernel(const int* __restrict__ counts,
                                 int* __restrict__ blockSums, int N) {
    int i = blockIdx.x * BS + threadIdx.x;
    int v = (i < N) ? counts[i] : 0;
    for (int o = 32; o > 0; o >>= 1) v += __shfl_down(v, o, 64);
    __shared__ int ws[BS / 64];
    int lane = threadIdx.x & 63, w = threadIdx.x >> 6;
    if (lane == 0) ws[w] = v;
    __syncthreads();
    if (threadIdx.x == 0) {
        int s = 0;
        for (int ww = 0; ww < BS / 64; ++ww) s += ws[ww];
        blockSums[blockIdx.x] = s;
    }
}

// Exclusive scan of up to 1024 block sums, single block of 1024 threads.
__global__ void scan_kernel(const int* __restrict__ blockSums,
                            int* __restrict__ blockOffsets, int nb) {
    __shared__ int tmp[1024];
    int t = threadIdx.x;
    int v = (t < nb) ? blockSums[t] : 0;
    tmp[t] = v;
    __syncthreads();
    for (int off = 1; off < 1024; off <<= 1) {
        int x = (t >= off) ? tmp[t - off] : 0;
        __syncthreads();
        tmp[t] += x;
        __syncthreads();
    }
    if (t < nb) blockOffsets[t] = tmp[t] - v;  // inclusive -> exclusive
}

__global__ void loss_kernel(const float* __restrict__ pred,
                            const float* __restrict__ gt,
                            const int* __restrict__ counts,
                            const int* __restrict__ blockOffsets,
                            double* __restrict__ sums, int N) {
    const int t = threadIdx.x;
    const int i = blockIdx.x * BS + t;
    const int lane = t & 63, w = t >> 6;
    int c = (i < N) ? counts[i] : 0;

    // block-level exclusive scan of c to get this row's gt offset
    int incl = c;
    for (int o = 1; o < 64; o <<= 1) {
        int x = __shfl_up(incl, o, 64);
        if (lane >= o) incl += x;
    }
    __shared__ int waveTot[BS / 64];
    if (lane == 63) waveTot[w] = incl;
    __syncthreads();
    int base = blockOffsets[blockIdx.x];
    for (int ww = 0; ww < w; ++ww) base += waveTot[ww];
    const int offset = base + incl - c;  // exclusive prefix for row i

    float lp = 0.f, la = 0.f, lw = 0.f, ls = 0.f;
    if (i < N && c > 0) {
        const float* p = pred + (size_t)i * 6;
        const float px = p[0], py = p[1];
        float best = 3.402823466e+38f;
        int bj = offset;
        for (int j = 0; j < c; ++j) {
            const float2 g = *reinterpret_cast<const float2*>(gt + (size_t)(offset + j) * 6);
            const float dx = px - g.x, dy = py - g.y;
            const float d2 = dx * dx + dy * dy;
            if (d2 < best) { best = d2; bj = offset + j; }
        }
        // loss_pos: max resp over segment == exp(-min sq_dist / (2 sigma^2))
        lp = 1.0f - expf(-best / 0.045f);

        const float* ng = gt + (size_t)bj * 6;
        const float a2 = ng[2], a3 = ng[3], a4 = ng[4], tt = ng[5];
        la = fabsf(p[2] - a2) + fabsf(p[3] - a3);
        const float d = p[4] - a4;
        const float ad = fabsf(d);
        lw = (ad < 1.0f) ? 0.5f * d * d : ad - 0.5f;
        const float x = p[5];
        if (tt > 0.0f) {
            ls = fmaxf(x, 0.0f) - x * tt + log1pf(expf(-fabsf(x)));
        }
    }

    // block reduction of 4 partials
    for (int o = 32; o > 0; o >>= 1) {
        lp += __shfl_down(lp, o, 64);
        la += __shfl_down(la, o, 64);
        lw += __shfl_down(lw, o, 64);
        ls += __shfl_down(ls, o, 64);
    }
    __shared__ float red[BS / 64][4];
    if (lane == 0) { red[w][0] = lp; red[w][1] = la; red[w][2] = lw; red[w][3] = ls; }
    __syncthreads();
    if (t == 0) {
        double s0 = 0, s1 = 0, s2 = 0, s3 = 0;
        for (int ww = 0; ww < BS / 64; ++ww) {
            s0 += (double)red[ww][0];
            s1 += (double)red[ww][1];
            s2 += (double)red[ww][2];
            s3 += (double)red[ww][3];
        }
        atomicAdd(&sums[0], s0);
        atomicAdd(&sums[1], s1);
        atomicAdd(&sums[2], s2);
        atomicAdd(&sums[3], s3);
    }
}

__global__ void finalize_kernel(const double* __restrict__ sums,
                                float* __restrict__ out, int N) {
    if (threadIdx.x == 0 && blockIdx.x == 0) {
        const double inv = 1.0 / (double)N;
        const float lp = (float)(sums[0] * inv);
        const float la = (float)(sums[1] * inv);
        const float lw = (float)(sums[2] * inv);
        const float ls = (float)(sums[3] * inv);
        out[0] = lp;
        out[1] = la;
        out[2] = lw;
        out[3] = ls;
        out[4] = lp + la + lw + 0.5f * ls;
    }
}

extern "C" void kernel_launch(void* const* d_in, const int* in_sizes, int n_in,
                              void* d_out, int out_size, void* d_ws, size_t ws_size,
                              hipStream_t stream) {
    const float* pred = (const float*)d_in[0];
    const float* gt = (const float*)d_in[1];
    const int* counts = (const int*)d_in[2];
    float* out = (float*)d_out;

    const int N = in_sizes[2];
    const int numBlocks = (N + BS - 1) / BS;  // 1024 for N=262144

    double* sums = (double*)d_ws;
    int* blockSums = (int*)((char*)d_ws + 64);
    int* blockOffsets = blockSums + numBlocks;

    hipMemsetAsync(d_ws, 0, 64, stream);
    block_sum_kernel<<<numBlocks, BS, 0, stream>>>(counts, blockSums, N);
    scan_kernel<<<1, 1024, 0, stream>>>(blockSums, blockOffsets, numBlocks);
    loss_kernel<<<numBlocks, BS, 0, stream>>>(pred, gt, counts, blockOffsets, sums, N);
    finalize_kernel<<<1, 1, 0, stream>>>(sums, out, N);
}

// Round 2
// 219.746 us; speedup vs baseline: 1.0352x; 1.0352x over previous
//
#include <hip/hip_runtime.h>
#include <math.h>
#include <float.h>

#define BS 256

// Workspace layout:
//   [0, 32)   : double sums[4] (lp, la, lw, ls)
//   [32, 36)  : int done-counter
//   [64, 64+4*nb)       : blockSums (int)
//   [64+4*nb, 64+8*nb)  : blockOffsets (int)

__global__ void block_sum_kernel(const int* __restrict__ counts,
                                 int* __restrict__ blockSums, int N) {
    int i = blockIdx.x * BS + threadIdx.x;
    int v = (i < N) ? counts[i] : 0;
    for (int o = 32; o > 0; o >>= 1) v += __shfl_down(v, o, 64);
    __shared__ int ws[BS / 64];
    int lane = threadIdx.x & 63, w = threadIdx.x >> 6;
    if (lane == 0) ws[w] = v;
    __syncthreads();
    if (threadIdx.x == 0) {
        int s = 0;
        for (int ww = 0; ww < BS / 64; ++ww) s += ws[ww];
        blockSums[blockIdx.x] = s;
    }
}

// Exclusive scan of up to 1024 block sums (single block), plus zero-init of
// the accumulator doubles and the done counter (d_ws is poisoned 0xAA).
__global__ void scan_kernel(const int* __restrict__ blockSums,
                            int* __restrict__ blockOffsets, int nb,
                            double* __restrict__ sums, int* __restrict__ done) {
    __shared__ int tmp[1024];
    int t = threadIdx.x;
    if (t < 4) sums[t] = 0.0;
    if (t == 4) *done = 0;
    int v = (t < nb) ? blockSums[t] : 0;
    tmp[t] = v;
    __syncthreads();
    for (int off = 1; off < 1024; off <<= 1) {
        int x = (t >= off) ? tmp[t - off] : 0;
        __syncthreads();
        tmp[t] += x;
        __syncthreads();
    }
    if (t < nb) blockOffsets[t] = tmp[t] - v;  // inclusive -> exclusive
}

__global__ void loss_kernel(const float* __restrict__ pred,
                            const float* __restrict__ gt,
                            const int* __restrict__ counts,
                            const int* __restrict__ blockOffsets,
                            double* __restrict__ sums, int* __restrict__ done,
                            float* __restrict__ out, int N, int numBlocks) {
    const int t = threadIdx.x;
    const int i = blockIdx.x * BS + t;
    const int lane = t & 63, w = t >> 6;
    int c = (i < N) ? counts[i] : 0;

    // block-level exclusive scan of c to get this row's gt offset
    int incl = c;
    for (int o = 1; o < 64; o <<= 1) {
        int x = __shfl_up(incl, o, 64);
        if (lane >= o) incl += x;
    }
    __shared__ int waveTot[BS / 64];
    if (lane == 63) waveTot[w] = incl;
    __syncthreads();
    int base = blockOffsets[blockIdx.x];
    for (int ww = 0; ww < w; ++ww) base += waveTot[ww];
    const int offset = base + incl - c;  // exclusive prefix for row i

    float lp = 0.f, la = 0.f, lw = 0.f, ls = 0.f;
    if (i < N && c > 0) {
        const float* p = pred + (size_t)i * 6;
        const float2 p01 = *reinterpret_cast<const float2*>(p);
        const float2 p23 = *reinterpret_cast<const float2*>(p + 2);
        const float2 p45 = *reinterpret_cast<const float2*>(p + 4);

        float best = FLT_MAX;
        int bj = offset;
        // Unrolled-by-8 with index clamp: 8 independent loads in flight.
        // Clamped duplicates repeat row c-1; strict < keeps the first
        // occurrence, so the lowest-index argmin (reference tie-break) holds.
        for (int j0 = 0; j0 < c; j0 += 8) {
            float2 g[8];
            int jj[8];
#pragma unroll
            for (int k = 0; k < 8; ++k) {
                int j = j0 + k;
                jj[k] = (j < c) ? j : (c - 1);
                g[k] = *reinterpret_cast<const float2*>(gt + (size_t)(offset + jj[k]) * 6);
            }
#pragma unroll
            for (int k = 0; k < 8; ++k) {
                const float dx = p01.x - g[k].x, dy = p01.y - g[k].y;
                const float d2 = dx * dx + dy * dy;
                if (d2 < best) { best = d2; bj = offset + jj[k]; }
            }
        }
        // max resp over segment == exp(-min sq_dist / (2 sigma^2))
        lp = 1.0f - expf(-best / 0.045f);

        const float* ng = gt + (size_t)bj * 6;
        const float2 g23 = *reinterpret_cast<const float2*>(ng + 2);
        const float2 g45 = *reinterpret_cast<const float2*>(ng + 4);
        la = fabsf(p23.x - g23.x) + fabsf(p23.y - g23.y);
        const float d = p45.x - g45.x;
        const float ad = fabsf(d);
        lw = (ad < 1.0f) ? 0.5f * d * d : ad - 0.5f;
        const float x = p45.y;
        if (g45.y > 0.0f) {
            ls = fmaxf(x, 0.0f) - x * g45.y + log1pf(expf(-fabsf(x)));
        }
    }

    // block reduction of 4 partials
    for (int o = 32; o > 0; o >>= 1) {
        lp += __shfl_down(lp, o, 64);
        la += __shfl_down(la, o, 64);
        lw += __shfl_down(lw, o, 64);
        ls += __shfl_down(ls, o, 64);
    }
    __shared__ float red[BS / 64][4];
    if (lane == 0) { red[w][0] = lp; red[w][1] = la; red[w][2] = lw; red[w][3] = ls; }
    __syncthreads();
    if (t == 0) {
        double s0 = 0, s1 = 0, s2 = 0, s3 = 0;
        for (int ww = 0; ww < BS / 64; ++ww) {
            s0 += (double)red[ww][0];
            s1 += (double)red[ww][1];
            s2 += (double)red[ww][2];
            s3 += (double)red[ww][3];
        }
        atomicAdd(&sums[0], s0);
        atomicAdd(&sums[1], s1);
        atomicAdd(&sums[2], s2);
        atomicAdd(&sums[3], s3);
        __threadfence();
        int prev = atomicAdd(done, 1);
        if (prev == numBlocks - 1) {
            // last block: coherent device-scope reads via atomic add of 0
            const double t0 = atomicAdd(&sums[0], 0.0);
            const double t1 = atomicAdd(&sums[1], 0.0);
            const double t2 = atomicAdd(&sums[2], 0.0);
            const double t3 = atomicAdd(&sums[3], 0.0);
            const double inv = 1.0 / (double)N;
            const float flp = (float)(t0 * inv);
            const float fla = (float)(t1 * inv);
            const float flw = (float)(t2 * inv);
            const float fls = (float)(t3 * inv);
            out[0] = flp;
            out[1] = fla;
            out[2] = flw;
            out[3] = fls;
            out[4] = flp + fla + flw + 0.5f * fls;
        }
    }
}

extern "C" void kernel_launch(void* const* d_in, const int* in_sizes, int n_in,
                              void* d_out, int out_size, void* d_ws, size_t ws_size,
                              hipStream_t stream) {
    const float* pred = (const float*)d_in[0];
    const float* gt = (const float*)d_in[1];
    const int* counts = (const int*)d_in[2];
    float* out = (float*)d_out;

    const int N = in_sizes[2];
    const int numBlocks = (N + BS - 1) / BS;  // 1024 for N=262144

    double* sums = (double*)d_ws;
    int* done = (int*)((char*)d_ws + 32);
    int* blockSums = (int*)((char*)d_ws + 64);
    int* blockOffsets = blockSums + numBlocks;

    block_sum_kernel<<<numBlocks, BS, 0, stream>>>(counts, blockSums, N);
    scan_kernel<<<1, 1024, 0, stream>>>(blockSums, blockOffsets, numBlocks, sums, done);
    loss_kernel<<<numBlocks, BS, 0, stream>>>(pred, gt, counts, blockOffsets,
                                              sums, done, out, N, numBlocks);
}